// Round 8
// baseline (230.905 us; speedup 1.0000x reference)
//
#include <hip/hip_runtime.h>
#include <hip/hip_bf16.h>
#include <cstdint>

#define DIM   1024
#define HEADS 16
#define HDIM  64
#define BATCH 2
#define SEQ   2048
#define ROWS  (BATCH*SEQ)   // 4096
static constexpr float QSCALE = 0.18033688f;        // HDIM^-0.5 * log2(e)

typedef float  f32x4  __attribute__((ext_vector_type(4)));
typedef float  float4v __attribute__((ext_vector_type(4)));
typedef __bf16 bf16x8 __attribute__((ext_vector_type(8)));
typedef __bf16 bf16x4 __attribute__((ext_vector_type(4)));
typedef short  short4v __attribute__((ext_vector_type(4)));

#if __has_builtin(__builtin_amdgcn_mfma_f32_16x16x16_bf16)
__device__ __forceinline__ f32x4 mfma16(bf16x4 a, bf16x4 b, f32x4 c) {
  return __builtin_amdgcn_mfma_f32_16x16x16_bf16(a, b, c, 0, 0, 0);
}
#else
__device__ __forceinline__ f32x4 mfma16(bf16x4 a, bf16x4 b, f32x4 c) {
  return __builtin_amdgcn_mfma_f32_16x16x16bf16_1k(
      __builtin_bit_cast(short4v, a), __builtin_bit_cast(short4v, b), c, 0, 0, 0);
}
#endif

// async global->LDS, 16B per lane; LDS dest is wave-uniform base + lane*16B
__device__ __forceinline__ void glds16(const __bf16* g, __bf16* l) {
  __builtin_amdgcn_global_load_lds(
      (const __attribute__((address_space(1))) void*)g,
      (__attribute__((address_space(3))) void*)l, 16, 0, 0);
}

// ---------------------------------------------------------------------------
// prep: z 0..7 -> fp32->bf16 convert of [x|y]; z == 8 -> W -> Wt[n][k] bf16.
// ---------------------------------------------------------------------------
__global__ __launch_bounds__(256) void prep_kernel(
    const float* __restrict__ x, const float* __restrict__ y,
    const float* __restrict__ Wq, const float* __restrict__ Wk,
    const float* __restrict__ Wv, const float* __restrict__ Wp,
    __bf16* __restrict__ xb, __bf16* __restrict__ yb, __bf16* __restrict__ Wt) {
  const int z = blockIdx.z, t = threadIdx.x;
  const size_t NEL = (size_t)ROWS * DIM;
  if (z < 8) {
    size_t idx = (((size_t)z * 1024 + blockIdx.x) * 256 + t) * 4;
    const float* s; __bf16* d;
    if (idx < NEL) { s = x + idx; d = xb + idx; }
    else           { s = y + (idx - NEL); d = yb + (idx - NEL); }
    const float4v v = *(const float4v*)s;
    bf16x4 o;
    o[0] = (__bf16)v[0]; o[1] = (__bf16)v[1]; o[2] = (__bf16)v[2]; o[3] = (__bf16)v[3];
    *(bf16x4*)d = o;
    return;
  }
  const int w = blockIdx.x >> 8, rem = blockIdx.x & 255;
  const float* W = (w == 0) ? Wq : (w == 1) ? Wk : (w == 2) ? Wv : Wp;
  __bf16* dst = Wt + (size_t)w * DIM * DIM;
  const int n0 = (rem & 15) * 64, k0 = (rem >> 4) * 64;
  __shared__ float T[64][65];
  const int col = t & 63, rw = t >> 6;
  #pragma unroll
  for (int p = 0; p < 16; ++p) {
    const int row = p * 4 + rw;
    T[row][col] = W[(size_t)(k0 + row) * DIM + n0 + col];
  }
  __syncthreads();
  #pragma unroll
  for (int p = 0; p < 16; ++p) {
    const int row = p * 4 + rw;
    dst[(size_t)(n0 + row) * DIM + k0 + col] = (__bf16)T[col][row];
  }
}

// ---------------------------------------------------------------------------
// gemm_bt: out[row,col] = scale * sum_k A[row][k] * Bt[col][k], bf16 out.
// 128x128 tile, BK=64, glds16 staging, XOR-swizzled LDS. Used for Q and K.
// ---------------------------------------------------------------------------
__global__ __launch_bounds__(256) void gemm_bt_kernel(
    const __bf16* __restrict__ A, const __bf16* __restrict__ Bt,
    __bf16* __restrict__ out, float scale) {
  __shared__ __bf16 As[128 * 64];
  __shared__ __bf16 Bs[128 * 64];

  const int t = threadIdx.x, lane = t & 63, wave = t >> 6;
  const int l15 = lane & 15, quad = lane >> 4;
  const int wm = wave & 1, wn = wave >> 1;
  const int rowBase = blockIdx.y * 128, colBase = blockIdx.x * 128;
  const int srow = lane >> 3;
  const int scol = ((lane & 7) ^ srow) * 8;

  f32x4 acc[4][4] = {};

  for (int kb = 0; kb < DIM; kb += 64) {
    __syncthreads();
    #pragma unroll
    for (int i = 0; i < 4; ++i) {
      const int c = wave * 4 + i;
      const int row = c * 8 + srow;
      glds16(&A[(size_t)(rowBase + row) * DIM + kb + scol], &As[c * 512]);
      glds16(&Bt[(size_t)(colBase + row) * DIM + kb + scol], &Bs[c * 512]);
    }
    __syncthreads();
    #pragma unroll
    for (int ks = 0; ks < 2; ++ks) {
      bf16x8 a[4], b[4];
      #pragma unroll
      for (int mi = 0; mi < 4; ++mi) {
        const int row = wm * 64 + mi * 16 + l15;
        a[mi] = *(const bf16x8*)&As[row * 64 + (((ks << 2) | quad) ^ (row & 7)) * 8];
      }
      #pragma unroll
      for (int ni = 0; ni < 4; ++ni) {
        const int row = wn * 64 + ni * 16 + l15;
        b[ni] = *(const bf16x8*)&Bs[row * 64 + (((ks << 2) | quad) ^ (row & 7)) * 8];
      }
      #pragma unroll
      for (int mi = 0; mi < 4; ++mi)
        #pragma unroll
        for (int ni = 0; ni < 4; ++ni)
          acc[mi][ni] = __builtin_amdgcn_mfma_f32_16x16x32_bf16(a[mi], b[ni], acc[mi][ni], 0, 0, 0);
    }
  }

  #pragma unroll
  for (int mi = 0; mi < 4; ++mi) {
    const int row0 = rowBase + wm * 64 + mi * 16 + quad * 4;
    #pragma unroll
    for (int ni = 0; ni < 4; ++ni) {
      const int col = colBase + wn * 64 + ni * 16 + l15;
      #pragma unroll
      for (int r = 0; r < 4; ++r)
        out[(size_t)(row0 + r) * DIM + col] = (__bf16)(acc[mi][ni][r] * scale);
    }
  }
}

// ---------------------------------------------------------------------------
// vproj: V = y @ Wv^T written TRANSPOSED to VT[(b*16+h)*64+d][key] with a
// swizzled in-LDS transpose for coalesced 16B stores.
// ---------------------------------------------------------------------------
__global__ __launch_bounds__(256) void vproj_kernel(
    const __bf16* __restrict__ A, const __bf16* __restrict__ Bt,
    __bf16* __restrict__ VT) {
  __shared__ __bf16 S[2][128 * 64];   // staging; reused as 128x128 transpose buf
  __bf16* As = S[0];
  __bf16* Bs = S[1];

  const int t = threadIdx.x, lane = t & 63, wave = t >> 6;
  const int l15 = lane & 15, quad = lane >> 4;
  const int wm = wave & 1, wn = wave >> 1;
  const int rowBase = blockIdx.y * 128, colBase = blockIdx.x * 128;
  const int srow = lane >> 3;
  const int scol = ((lane & 7) ^ srow) * 8;

  f32x4 acc[4][4] = {};

  for (int kb = 0; kb < DIM; kb += 64) {
    __syncthreads();
    #pragma unroll
    for (int i = 0; i < 4; ++i) {
      const int c = wave * 4 + i;
      const int row = c * 8 + srow;
      glds16(&A[(size_t)(rowBase + row) * DIM + kb + scol], &As[c * 512]);
      glds16(&Bt[(size_t)(colBase + row) * DIM + kb + scol], &Bs[c * 512]);
    }
    __syncthreads();
    #pragma unroll
    for (int ks = 0; ks < 2; ++ks) {
      bf16x8 a[4], b[4];
      #pragma unroll
      for (int mi = 0; mi < 4; ++mi) {
        const int row = wm * 64 + mi * 16 + l15;
        a[mi] = *(const bf16x8*)&As[row * 64 + (((ks << 2) | quad) ^ (row & 7)) * 8];
      }
      #pragma unroll
      for (int ni = 0; ni < 4; ++ni) {
        const int row = wn * 64 + ni * 16 + l15;
        b[ni] = *(const bf16x8*)&Bs[row * 64 + (((ks << 2) | quad) ^ (row & 7)) * 8];
      }
      #pragma unroll
      for (int mi = 0; mi < 4; ++mi)
        #pragma unroll
        for (int ni = 0; ni < 4; ++ni)
          acc[mi][ni] = __builtin_amdgcn_mfma_f32_16x16x32_bf16(a[mi], b[ni], acc[mi][ni], 0, 0, 0);
    }
  }

  // transpose epilogue: Ts element (d,k) at d*128 + ((k>>3)^(d&7))*8 + (k&7)
  __syncthreads();
  __bf16* Ts = &S[0][0];              // 128x128 bf16 = 32 KB exactly
  #pragma unroll
  for (int mi = 0; mi < 4; ++mi) {
    const int bk3 = wm * 8 + mi * 2 + (quad >> 1);   // (key_local >> 3)
    #pragma unroll
    for (int ni = 0; ni < 4; ++ni) {
      const int dl = wn * 64 + ni * 16 + l15;        // d_local
      bf16x4 pk;
      #pragma unroll
      for (int r = 0; r < 4; ++r) pk[r] = (__bf16)acc[mi][ni][r];
      *(bf16x4*)&Ts[dl * 128 + (bk3 ^ (dl & 7)) * 8 + (quad & 1) * 4] = pk;
    }
  }
  __syncthreads();
  // read out: thread t -> d = t>>1, key-half = t&1; 8 x 16B coalesced stores
  const int d = t >> 1, khh = t & 1;
  const size_t vrow = (size_t)((rowBase >> 11) * HEADS * HDIM) + colBase + d;
  const int key0g = rowBase & (SEQ - 1);
  #pragma unroll
  for (int j = 0; j < 8; ++j) {
    const int kc = khh * 8 + j;
    const int lc = (kc & 8) | ((kc ^ d) & 7);
    const bf16x8 v = *(const bf16x8*)&Ts[d * 128 + lc * 8];
    *(bf16x8*)&VT[vrow * SEQ + key0g + kc * 8] = v;
  }
}

// ---------------------------------------------------------------------------
// Flash attention v5 (unchanged from R7): register-P, K=16 PV MFMAs.
// ---------------------------------------------------------------------------
__global__ __launch_bounds__(256, 2) void attn_kernel(
    const __bf16* __restrict__ Qb, const __bf16* __restrict__ Kb,
    const __bf16* __restrict__ VT, __bf16* __restrict__ Ob) {
  __shared__ __bf16 KV[2][2][64 * 64];
  __shared__ float lb[2][128];

  const int t = threadIdx.x, lane = t & 63, wave = t >> 6;
  const int l15 = lane & 15, quad = lane >> 4;
  const int bh = blockIdx.y, b = bh >> 4, h = bh & 15;
  const int qseg = wave & 1, kh = wave >> 1;
  const int qrow0 = blockIdx.x * 128 + qseg * 64;
  const int srow = lane >> 3;
  const int scol = ((lane & 7) ^ srow) * 8;

  const __bf16* Kbh = Kb + (size_t)b * SEQ * DIM + h * HDIM;
  const __bf16* Vbh = VT + (size_t)bh * HDIM * SEQ;

  bf16x8 qf[4][2];
  #pragma unroll
  for (int mi = 0; mi < 4; ++mi)
    #pragma unroll
    for (int ks = 0; ks < 2; ++ks)
      qf[mi][ks] = *(const bf16x8*)&Qb[(size_t)(b * SEQ + qrow0 + mi * 16 + l15) * DIM
                                       + h * HDIM + ks * 32 + quad * 8];

  f32x4 o[4][4] = {};
  float lsum[4] = {};

  auto stage = [&](int jb, int buf) {
    #pragma unroll
    for (int i = 0; i < 2; ++i) {
      const int c = wave * 2 + i;
      const int row = c * 8 + srow;
      glds16(&Kbh[(size_t)(jb + row) * DIM + scol], &KV[buf][0][c * 512]);
      glds16(&Vbh[(size_t)row * SEQ + jb + scol], &KV[buf][1][c * 512]);
    }
  };

  stage(0, 0);
  for (int j = 0; j < SEQ / 64; ++j) {
    const int buf = j & 1;
    __syncthreads();
    if (j + 1 < SEQ / 64) stage((j + 1) * 64, buf ^ 1);
    const __bf16* Ks = KV[buf][0];
    const __bf16* Vs = KV[buf][1];

    f32x4 sT[2][4] = {};
    #pragma unroll
    for (int ks = 0; ks < 2; ++ks)
      #pragma unroll
      for (int ni = 0; ni < 2; ++ni) {
        const int key = kh * 32 + ni * 16 + l15;
        const bf16x8 kf = *(const bf16x8*)&Ks[key * 64 + (((ks << 2) | quad) ^ (key & 7)) * 8];
        #pragma unroll
        for (int mi = 0; mi < 4; ++mi)
          sT[ni][mi] = __builtin_amdgcn_mfma_f32_16x16x32_bf16(kf, qf[mi][ks], sT[ni][mi], 0, 0, 0);
      }

    bf16x4 pa[2][4];
    #pragma unroll
    for (int ni = 0; ni < 2; ++ni)
      #pragma unroll
      for (int mi = 0; mi < 4; ++mi)
        #pragma unroll
        for (int r = 0; r < 4; ++r) {
          const float pv = __builtin_amdgcn_exp2f(sT[ni][mi][r]);
          lsum[mi] += pv;
          pa[ni][mi][r] = (__bf16)pv;
        }

    #pragma unroll
    for (int ni = 0; ni < 2; ++ni) {
      const int key0 = kh * 32 + ni * 16;
      #pragma unroll
      for (int dt = 0; dt < 4; ++dt) {
        const int d = dt * 16 + l15;
        const bf16x4 vf = *(const bf16x4*)&Vs[d * 64
            + (((key0 >> 3) + (quad >> 1)) ^ (d & 7)) * 8 + (quad & 1) * 4];
        #pragma unroll
        for (int mi = 0; mi < 4; ++mi)
          o[mi][dt] = mfma16(pa[ni][mi], vf, o[mi][dt]);
      }
    }
  }

  #pragma unroll
  for (int mi = 0; mi < 4; ++mi) {
    lsum[mi] += __shfl_xor(lsum[mi], 16, 64);
    lsum[mi] += __shfl_xor(lsum[mi], 32, 64);
  }
  __syncthreads();
  float* mb = (float*)&KV[0][0][0];
  if (quad == 0) {
    #pragma unroll
    for (int mi = 0; mi < 4; ++mi)
      lb[kh][qseg * 64 + mi * 16 + l15] = lsum[mi];
  }
  if (kh == 1) {
    #pragma unroll
    for (int mi = 0; mi < 4; ++mi)
      #pragma unroll
      for (int r = 0; r < 4; ++r) {
        const int q = mi * 16 + quad * 4 + r;
        #pragma unroll
        for (int dt = 0; dt < 4; ++dt)
          mb[qseg * 4096 + q * 64 + dt * 16 + l15] = o[mi][dt][r];
      }
  }
  __syncthreads();
  if (kh == 0) {
    #pragma unroll
    for (int mi = 0; mi < 4; ++mi)
      #pragma unroll
      for (int r = 0; r < 4; ++r) {
        const int q = mi * 16 + quad * 4 + r;
        const float inv = 1.f / (lb[0][qseg * 64 + q] + lb[1][qseg * 64 + q]);
        const size_t row = (size_t)(b * SEQ + qrow0 + q);
        #pragma unroll
        for (int dt = 0; dt < 4; ++dt) {
          const float ov = o[mi][dt][r] + mb[qseg * 4096 + q * 64 + dt * 16 + l15];
          Ob[row * DIM + h * HDIM + dt * 16 + l15] = (__bf16)(ov * inv);
        }
      }
  }
}

// ---------------------------------------------------------------------------
// Output projection: 64x128 tile (512 blocks = 2/CU), fp32 out + bias.
// ---------------------------------------------------------------------------
__global__ __launch_bounds__(256) void outproj_kernel(
    const __bf16* __restrict__ A, const __bf16* __restrict__ Bt,
    const float* __restrict__ bias, float* __restrict__ out) {
  __shared__ __bf16 As[64 * 64];
  __shared__ __bf16 Bs[128 * 64];

  const int t = threadIdx.x, lane = t & 63, wave = t >> 6;
  const int l15 = lane & 15, quad = lane >> 4;
  const int wm = wave & 1, wn = wave >> 1;
  const int rowBase = blockIdx.y * 64, colBase = blockIdx.x * 128;
  const int srow = lane >> 3;
  const int scol = ((lane & 7) ^ srow) * 8;

  f32x4 acc[2][4] = {};

  for (int kb = 0; kb < DIM; kb += 64) {
    __syncthreads();
    #pragma unroll
    for (int i = 0; i < 2; ++i) {
      const int c = wave * 2 + i;          // 8 A-chunks
      const int row = c * 8 + srow;
      glds16(&A[(size_t)(rowBase + row) * DIM + kb + scol], &As[c * 512]);
    }
    #pragma unroll
    for (int i = 0; i < 4; ++i) {
      const int c = wave * 4 + i;          // 16 B-chunks
      const int row = c * 8 + srow;
      glds16(&Bt[(size_t)(colBase + row) * DIM + kb + scol], &Bs[c * 512]);
    }
    __syncthreads();
    #pragma unroll
    for (int ks = 0; ks < 2; ++ks) {
      bf16x8 a[2], b[4];
      #pragma unroll
      for (int mi = 0; mi < 2; ++mi) {
        const int row = wm * 32 + mi * 16 + l15;
        a[mi] = *(const bf16x8*)&As[row * 64 + (((ks << 2) | quad) ^ (row & 7)) * 8];
      }
      #pragma unroll
      for (int ni = 0; ni < 4; ++ni) {
        const int row = wn * 64 + ni * 16 + l15;
        b[ni] = *(const bf16x8*)&Bs[row * 64 + (((ks << 2) | quad) ^ (row & 7)) * 8];
      }
      #pragma unroll
      for (int mi = 0; mi < 2; ++mi)
        #pragma unroll
        for (int ni = 0; ni < 4; ++ni)
          acc[mi][ni] = __builtin_amdgcn_mfma_f32_16x16x32_bf16(a[mi], b[ni], acc[mi][ni], 0, 0, 0);
    }
  }

  #pragma unroll
  for (int mi = 0; mi < 2; ++mi) {
    const int row0 = rowBase + wm * 32 + mi * 16 + quad * 4;
    #pragma unroll
    for (int ni = 0; ni < 4; ++ni) {
      const int col = colBase + wn * 64 + ni * 16 + l15;
      const float bb = bias[col];
      #pragma unroll
      for (int r = 0; r < 4; ++r)
        out[(size_t)(row0 + r) * DIM + col] = acc[mi][ni][r] + bb;
    }
  }
}

// ---------------------------------------------------------------------------
// ws layout (bf16, NEL = 4194304): xb yb Wt[4MB-elems] Qb Kb VT = 50.3 MB.
// Ob aliases xb (dead after projections).
// ---------------------------------------------------------------------------
extern "C" void kernel_launch(void* const* d_in, const int* in_sizes, int n_in,
                              void* d_out, int out_size, void* d_ws, size_t ws_size,
                              hipStream_t stream) {
  const float* x  = (const float*)d_in[0];
  const float* y  = (const float*)d_in[1];
  const float* Wq = (const float*)d_in[2];
  const float* Wk = (const float*)d_in[3];
  const float* Wv = (const float*)d_in[4];
  const float* Wp = (const float*)d_in[5];
  const float* bp = (const float*)d_in[6];
  float* out = (float*)d_out;

  const size_t NEL = (size_t)ROWS * DIM;
  __bf16* xb = (__bf16*)d_ws;
  __bf16* yb = xb + NEL;
  __bf16* Wt = yb + NEL;            // [4][1024][1024] (q,k,v,p), transposed [n][k]
  __bf16* Qb = Wt + NEL;
  __bf16* Kb = Qb + NEL;
  __bf16* VT = Kb + NEL;
  __bf16* Ob = xb;                  // alias: xb dead after projections

  prep_kernel<<<dim3(1024, 1, 9), 256, 0, stream>>>(x, y, Wq, Wk, Wv, Wp, xb, yb, Wt);
  gemm_bt_kernel<<<dim3(DIM / 128, ROWS / 128), 256, 0, stream>>>(xb, Wt, Qb, QSCALE);
  gemm_bt_kernel<<<dim3(DIM / 128, ROWS / 128), 256, 0, stream>>>(yb, Wt + NEL / 4, Kb, 1.0f);
  vproj_kernel<<<dim3(DIM / 128, ROWS / 128), 256, 0, stream>>>(yb, Wt + NEL / 2, VT);
  attn_kernel<<<dim3(SEQ / 128, BATCH * HEADS), 256, 0, stream>>>(Qb, Kb, VT, Ob);
  outproj_kernel<<<dim3(DIM / 128, ROWS / 64), 256, 0, stream>>>(Ob, Wt + 3 * NEL / 4, bp, out);
}

// Round 9
// 212.376 us; speedup vs baseline: 1.0872x; 1.0872x over previous
//
#include <hip/hip_runtime.h>
#include <hip/hip_bf16.h>
#include <cstdint>

#define DIM   1024
#define HEADS 16
#define HDIM  64
#define BATCH 2
#define SEQ   2048
#define ROWS  (BATCH*SEQ)   // 4096
static constexpr float QSCALE = 0.18033688f;        // HDIM^-0.5 * log2(e)

typedef float  f32x4  __attribute__((ext_vector_type(4)));
typedef float  float4v __attribute__((ext_vector_type(4)));
typedef __bf16 bf16x8 __attribute__((ext_vector_type(8)));
typedef __bf16 bf16x4 __attribute__((ext_vector_type(4)));
typedef short  short4v __attribute__((ext_vector_type(4)));

#if __has_builtin(__builtin_amdgcn_mfma_f32_16x16x16_bf16)
__device__ __forceinline__ f32x4 mfma16(bf16x4 a, bf16x4 b, f32x4 c) {
  return __builtin_amdgcn_mfma_f32_16x16x16_bf16(a, b, c, 0, 0, 0);
}
#else
__device__ __forceinline__ f32x4 mfma16(bf16x4 a, bf16x4 b, f32x4 c) {
  return __builtin_amdgcn_mfma_f32_16x16x16bf16_1k(
      __builtin_bit_cast(short4v, a), __builtin_bit_cast(short4v, b), c, 0, 0, 0);
}
#endif

// async global->LDS, 16B per lane; LDS dest is wave-uniform base + lane*16B
__device__ __forceinline__ void glds16(const __bf16* g, __bf16* l) {
  __builtin_amdgcn_global_load_lds(
      (const __attribute__((address_space(1))) void*)g,
      (__attribute__((address_space(3))) void*)l, 16, 0, 0);
}

// ---------------------------------------------------------------------------
// prep: z 0..7 -> fp32->bf16 convert of [x|y]; z == 8 -> W -> Wt[n][k] bf16.
// ---------------------------------------------------------------------------
__global__ __launch_bounds__(256) void prep_kernel(
    const float* __restrict__ x, const float* __restrict__ y,
    const float* __restrict__ Wq, const float* __restrict__ Wk,
    const float* __restrict__ Wv, const float* __restrict__ Wp,
    __bf16* __restrict__ xb, __bf16* __restrict__ yb, __bf16* __restrict__ Wt) {
  const int z = blockIdx.z, t = threadIdx.x;
  const size_t NEL = (size_t)ROWS * DIM;
  if (z < 8) {
    size_t idx = (((size_t)z * 1024 + blockIdx.x) * 256 + t) * 4;
    const float* s; __bf16* d;
    if (idx < NEL) { s = x + idx; d = xb + idx; }
    else           { s = y + (idx - NEL); d = yb + (idx - NEL); }
    const float4v v = *(const float4v*)s;
    bf16x4 o;
    o[0] = (__bf16)v[0]; o[1] = (__bf16)v[1]; o[2] = (__bf16)v[2]; o[3] = (__bf16)v[3];
    *(bf16x4*)d = o;
    return;
  }
  const int w = blockIdx.x >> 8, rem = blockIdx.x & 255;
  const float* W = (w == 0) ? Wq : (w == 1) ? Wk : (w == 2) ? Wv : Wp;
  __bf16* dst = Wt + (size_t)w * DIM * DIM;
  const int n0 = (rem & 15) * 64, k0 = (rem >> 4) * 64;
  __shared__ float T[64][65];
  const int col = t & 63, rw = t >> 6;
  #pragma unroll
  for (int p = 0; p < 16; ++p) {
    const int row = p * 4 + rw;
    T[row][col] = W[(size_t)(k0 + row) * DIM + n0 + col];
  }
  __syncthreads();
  #pragma unroll
  for (int p = 0; p < 16; ++p) {
    const int row = p * 4 + rw;
    dst[(size_t)(n0 + row) * DIM + k0 + col] = (__bf16)T[col][row];
  }
}

// ---------------------------------------------------------------------------
// Fused QKV projection, one 768-block dispatch (3 blocks/CU).
// z: 0 -> Q = xb@Wq^T * QSCALE, 1 -> K = yb@Wk^T, 2 -> V = yb@Wv^T written
// TRANSPOSED to VT[(b*16+h)*64+d][key] via swizzled in-LDS transpose.
// ---------------------------------------------------------------------------
__global__ __launch_bounds__(256) void proj_kernel(
    const __bf16* __restrict__ xb, const __bf16* __restrict__ yb,
    const __bf16* __restrict__ Wt,
    __bf16* __restrict__ Qb, __bf16* __restrict__ Kb, __bf16* __restrict__ VT) {
  const int z = blockIdx.z;
  const __bf16* A = (z == 0) ? xb : yb;
  const __bf16* Bt = Wt + (size_t)z * DIM * DIM;

  __shared__ __bf16 S[2][128 * 64];   // staging; S[0..1] reused for transpose
  __bf16* As = S[0];
  __bf16* Bs = S[1];

  const int t = threadIdx.x, lane = t & 63, wave = t >> 6;
  const int l15 = lane & 15, quad = lane >> 4;
  const int wm = wave & 1, wn = wave >> 1;
  const int rowBase = blockIdx.y * 128, colBase = blockIdx.x * 128;
  const int srow = lane >> 3;
  const int scol = ((lane & 7) ^ srow) * 8;

  f32x4 acc[4][4] = {};

  for (int kb = 0; kb < DIM; kb += 64) {
    __syncthreads();
    #pragma unroll
    for (int i = 0; i < 4; ++i) {
      const int c = wave * 4 + i;
      const int row = c * 8 + srow;
      glds16(&A[(size_t)(rowBase + row) * DIM + kb + scol], &As[c * 512]);
      glds16(&Bt[(size_t)(colBase + row) * DIM + kb + scol], &Bs[c * 512]);
    }
    __syncthreads();
    #pragma unroll
    for (int ks = 0; ks < 2; ++ks) {
      bf16x8 a[4], b[4];
      #pragma unroll
      for (int mi = 0; mi < 4; ++mi) {
        const int row = wm * 64 + mi * 16 + l15;
        a[mi] = *(const bf16x8*)&As[row * 64 + (((ks << 2) | quad) ^ (row & 7)) * 8];
      }
      #pragma unroll
      for (int ni = 0; ni < 4; ++ni) {
        const int row = wn * 64 + ni * 16 + l15;
        b[ni] = *(const bf16x8*)&Bs[row * 64 + (((ks << 2) | quad) ^ (row & 7)) * 8];
      }
      #pragma unroll
      for (int mi = 0; mi < 4; ++mi)
        #pragma unroll
        for (int ni = 0; ni < 4; ++ni)
          acc[mi][ni] = __builtin_amdgcn_mfma_f32_16x16x32_bf16(a[mi], b[ni], acc[mi][ni], 0, 0, 0);
    }
  }

  if (z < 2) {
    __bf16* out = (z == 0) ? Qb : Kb;
    const float sc = (z == 0) ? QSCALE : 1.0f;
    #pragma unroll
    for (int mi = 0; mi < 4; ++mi) {
      const int row0 = rowBase + wm * 64 + mi * 16 + quad * 4;
      #pragma unroll
      for (int ni = 0; ni < 4; ++ni) {
        const int col = colBase + wn * 64 + ni * 16 + l15;
        #pragma unroll
        for (int r = 0; r < 4; ++r)
          out[(size_t)(row0 + r) * DIM + col] = (__bf16)(acc[mi][ni][r] * sc);
      }
    }
    return;
  }

  // z == 2: transpose epilogue (verified R8). Ts element (d,k) at
  // d*128 + ((k>>3)^(d&7))*8 + (k&7); rows=keys, cols=d.
  __syncthreads();
  __bf16* Ts = &S[0][0];              // 128x128 bf16 = 32 KB
  #pragma unroll
  for (int mi = 0; mi < 4; ++mi) {
    const int bk3 = wm * 8 + mi * 2 + (quad >> 1);   // key_local >> 3
    #pragma unroll
    for (int ni = 0; ni < 4; ++ni) {
      const int dl = wn * 64 + ni * 16 + l15;        // d_local
      bf16x4 pk;
      #pragma unroll
      for (int r = 0; r < 4; ++r) pk[r] = (__bf16)acc[mi][ni][r];
      *(bf16x4*)&Ts[dl * 128 + (bk3 ^ (dl & 7)) * 8 + (quad & 1) * 4] = pk;
    }
  }
  __syncthreads();
  const int d = t >> 1, khh = t & 1;
  const size_t vrow = (size_t)((rowBase >> 11) * HEADS * HDIM) + colBase + d;
  const int key0g = rowBase & (SEQ - 1);
  #pragma unroll
  for (int j = 0; j < 8; ++j) {
    const int kc = khh * 8 + j;
    const int lc = (kc & 8) | ((kc ^ d) & 7);
    const bf16x8 v = *(const bf16x8*)&Ts[d * 128 + lc * 8];
    *(bf16x8*)&VT[vrow * SEQ + key0g + kc * 8] = v;
  }
}

// ---------------------------------------------------------------------------
// Flash attention v6: register-P (C-layout == A16-layout), row sums via
// K=16 ones-MFMA (lacc in C-layout row=q, matching o) -> zero cross-lane ops.
// Block = 4 waves, 128 q-rows; wave (qseg, kh) does 64q x 32keys.
// Double-buffered K/V staging, one barrier per 64-key tile.
// ---------------------------------------------------------------------------
__global__ __launch_bounds__(256, 2) void attn_kernel(
    const __bf16* __restrict__ Qb, const __bf16* __restrict__ Kb,
    const __bf16* __restrict__ VT, __bf16* __restrict__ Ob) {
  __shared__ __bf16 KV[2][2][64 * 64];
  __shared__ float lb[2][128];

  const int t = threadIdx.x, lane = t & 63, wave = t >> 6;
  const int l15 = lane & 15, quad = lane >> 4;
  const int bh = blockIdx.y, b = bh >> 4, h = bh & 15;
  const int qseg = wave & 1, kh = wave >> 1;
  const int qrow0 = blockIdx.x * 128 + qseg * 64;
  const int srow = lane >> 3;
  const int scol = ((lane & 7) ^ srow) * 8;

  const __bf16* Kbh = Kb + (size_t)b * SEQ * DIM + h * HDIM;
  const __bf16* Vbh = VT + (size_t)bh * HDIM * SEQ;

  bf16x8 qf[4][2];
  #pragma unroll
  for (int mi = 0; mi < 4; ++mi)
    #pragma unroll
    for (int ks = 0; ks < 2; ++ks)
      qf[mi][ks] = *(const bf16x8*)&Qb[(size_t)(b * SEQ + qrow0 + mi * 16 + l15) * DIM
                                       + h * HDIM + ks * 32 + quad * 8];

  bf16x4 ones4;
  #pragma unroll
  for (int i = 0; i < 4; ++i) ones4[i] = (__bf16)1.0f;

  f32x4 o[4][4] = {};      // o[mi][dt]: col=d(l15), row=q(quad*4+r)
  f32x4 lacc[4] = {};      // row sums, C-layout: row=q(quad*4+r), cols dup

  auto stage = [&](int jb, int buf) {
    #pragma unroll
    for (int i = 0; i < 2; ++i) {
      const int c = wave * 2 + i;
      const int row = c * 8 + srow;
      glds16(&Kbh[(size_t)(jb + row) * DIM + scol], &KV[buf][0][c * 512]);
      glds16(&Vbh[(size_t)row * SEQ + jb + scol], &KV[buf][1][c * 512]);
    }
  };

  stage(0, 0);
  for (int j = 0; j < SEQ / 64; ++j) {
    const int buf = j & 1;
    __syncthreads();
    if (j + 1 < SEQ / 64) stage((j + 1) * 64, buf ^ 1);
    const __bf16* Ks = KV[buf][0];
    const __bf16* Vs = KV[buf][1];

    f32x4 sT[2][4] = {};
    #pragma unroll
    for (int ks = 0; ks < 2; ++ks)
      #pragma unroll
      for (int ni = 0; ni < 2; ++ni) {
        const int key = kh * 32 + ni * 16 + l15;
        const bf16x8 kf = *(const bf16x8*)&Ks[key * 64 + (((ks << 2) | quad) ^ (key & 7)) * 8];
        #pragma unroll
        for (int mi = 0; mi < 4; ++mi)
          sT[ni][mi] = __builtin_amdgcn_mfma_f32_16x16x32_bf16(kf, qf[mi][ks], sT[ni][mi], 0, 0, 0);
      }

    // p = 2^sT straight into A-frags of the K=16 MFMAs
    bf16x4 pa[2][4];
    #pragma unroll
    for (int ni = 0; ni < 2; ++ni)
      #pragma unroll
      for (int mi = 0; mi < 4; ++mi)
        #pragma unroll
        for (int r = 0; r < 4; ++r)
          pa[ni][mi][r] = (__bf16)__builtin_amdgcn_exp2f(sT[ni][mi][r]);

    // O += P V ; lacc += P * 1 (row sums on the MFMA pipe)
    #pragma unroll
    for (int ni = 0; ni < 2; ++ni) {
      const int key0 = kh * 32 + ni * 16;
      #pragma unroll
      for (int mi = 0; mi < 4; ++mi)
        lacc[mi] = mfma16(pa[ni][mi], ones4, lacc[mi]);
      #pragma unroll
      for (int dt = 0; dt < 4; ++dt) {
        const int d = dt * 16 + l15;
        const bf16x4 vf = *(const bf16x4*)&Vs[d * 64
            + (((key0 >> 3) + (quad >> 1)) ^ (d & 7)) * 8 + (quad & 1) * 4];
        #pragma unroll
        for (int mi = 0; mi < 4; ++mi)
          o[mi][dt] = mfma16(pa[ni][mi], vf, o[mi][dt]);
      }
    }
  }

  // merge key-halves; lacc row=q matches o row=q (no cross-lane ops)
  __syncthreads();
  float* mb = (float*)&KV[0][0][0];
  if (l15 == 0) {
    #pragma unroll
    for (int mi = 0; mi < 4; ++mi)
      #pragma unroll
      for (int r = 0; r < 4; ++r)
        lb[kh][qseg * 64 + mi * 16 + quad * 4 + r] = lacc[mi][r];
  }
  if (kh == 1) {
    #pragma unroll
    for (int mi = 0; mi < 4; ++mi)
      #pragma unroll
      for (int r = 0; r < 4; ++r) {
        const int q = mi * 16 + quad * 4 + r;
        #pragma unroll
        for (int dt = 0; dt < 4; ++dt)
          mb[qseg * 4096 + q * 64 + dt * 16 + l15] = o[mi][dt][r];
      }
  }
  __syncthreads();
  if (kh == 0) {
    #pragma unroll
    for (int mi = 0; mi < 4; ++mi)
      #pragma unroll
      for (int r = 0; r < 4; ++r) {
        const int q = mi * 16 + quad * 4 + r;
        const float inv = 1.f / (lb[0][qseg * 64 + q] + lb[1][qseg * 64 + q]);
        const size_t row = (size_t)(b * SEQ + qrow0 + q);
        #pragma unroll
        for (int dt = 0; dt < 4; ++dt) {
          const float ov = o[mi][dt][r] + mb[qseg * 4096 + q * 64 + dt * 16 + l15];
          Ob[row * DIM + h * HDIM + dt * 16 + l15] = (__bf16)(ov * inv);
        }
      }
  }
}

// ---------------------------------------------------------------------------
// Output projection: 64x128 tile (512 blocks = 2/CU), fp32 out + bias.
// ---------------------------------------------------------------------------
__global__ __launch_bounds__(256) void outproj_kernel(
    const __bf16* __restrict__ A, const __bf16* __restrict__ Bt,
    const float* __restrict__ bias, float* __restrict__ out) {
  __shared__ __bf16 As[64 * 64];
  __shared__ __bf16 Bs[128 * 64];

  const int t = threadIdx.x, lane = t & 63, wave = t >> 6;
  const int l15 = lane & 15, quad = lane >> 4;
  const int wm = wave & 1, wn = wave >> 1;
  const int rowBase = blockIdx.y * 64, colBase = blockIdx.x * 128;
  const int srow = lane >> 3;
  const int scol = ((lane & 7) ^ srow) * 8;

  f32x4 acc[2][4] = {};

  for (int kb = 0; kb < DIM; kb += 64) {
    __syncthreads();
    #pragma unroll
    for (int i = 0; i < 2; ++i) {
      const int c = wave * 2 + i;
      const int row = c * 8 + srow;
      glds16(&A[(size_t)(rowBase + row) * DIM + kb + scol], &As[c * 512]);
    }
    #pragma unroll
    for (int i = 0; i < 4; ++i) {
      const int c = wave * 4 + i;
      const int row = c * 8 + srow;
      glds16(&Bt[(size_t)(colBase + row) * DIM + kb + scol], &Bs[c * 512]);
    }
    __syncthreads();
    #pragma unroll
    for (int ks = 0; ks < 2; ++ks) {
      bf16x8 a[2], b[4];
      #pragma unroll
      for (int mi = 0; mi < 2; ++mi) {
        const int row = wm * 32 + mi * 16 + l15;
        a[mi] = *(const bf16x8*)&As[row * 64 + (((ks << 2) | quad) ^ (row & 7)) * 8];
      }
      #pragma unroll
      for (int ni = 0; ni < 4; ++ni) {
        const int row = wn * 64 + ni * 16 + l15;
        b[ni] = *(const bf16x8*)&Bs[row * 64 + (((ks << 2) | quad) ^ (row & 7)) * 8];
      }
      #pragma unroll
      for (int mi = 0; mi < 2; ++mi)
        #pragma unroll
        for (int ni = 0; ni < 4; ++ni)
          acc[mi][ni] = __builtin_amdgcn_mfma_f32_16x16x32_bf16(a[mi], b[ni], acc[mi][ni], 0, 0, 0);
    }
  }

  #pragma unroll
  for (int mi = 0; mi < 2; ++mi) {
    const int row0 = rowBase + wm * 32 + mi * 16 + quad * 4;
    #pragma unroll
    for (int ni = 0; ni < 4; ++ni) {
      const int col = colBase + wn * 64 + ni * 16 + l15;
      const float bb = bias[col];
      #pragma unroll
      for (int r = 0; r < 4; ++r)
        out[(size_t)(row0 + r) * DIM + col] = acc[mi][ni][r] + bb;
    }
  }
}

// ---------------------------------------------------------------------------
// ws layout (bf16, NEL = 4194304): xb yb Wt[4M] Qb Kb VT = 50.3 MB.
// Ob aliases xb (dead after projections).
// ---------------------------------------------------------------------------
extern "C" void kernel_launch(void* const* d_in, const int* in_sizes, int n_in,
                              void* d_out, int out_size, void* d_ws, size_t ws_size,
                              hipStream_t stream) {
  const float* x  = (const float*)d_in[0];
  const float* y  = (const float*)d_in[1];
  const float* Wq = (const float*)d_in[2];
  const float* Wk = (const float*)d_in[3];
  const float* Wv = (const float*)d_in[4];
  const float* Wp = (const float*)d_in[5];
  const float* bp = (const float*)d_in[6];
  float* out = (float*)d_out;

  const size_t NEL = (size_t)ROWS * DIM;
  __bf16* xb = (__bf16*)d_ws;
  __bf16* yb = xb + NEL;
  __bf16* Wt = yb + NEL;            // [4][1024][1024] (q,k,v,p), transposed [n][k]
  __bf16* Qb = Wt + NEL;
  __bf16* Kb = Qb + NEL;
  __bf16* VT = Kb + NEL;
  __bf16* Ob = xb;                  // alias: xb dead after projections

  prep_kernel<<<dim3(1024, 1, 9), 256, 0, stream>>>(x, y, Wq, Wk, Wv, Wp, xb, yb, Wt);
  proj_kernel<<<dim3(DIM / 128, ROWS / 128, 3), 256, 0, stream>>>(xb, yb, Wt, Qb, Kb, VT);
  attn_kernel<<<dim3(SEQ / 128, BATCH * HEADS), 256, 0, stream>>>(Qb, Kb, VT, Ob);
  outproj_kernel<<<dim3(DIM / 128, ROWS / 64), 256, 0, stream>>>(Ob, Wt + 3 * NEL / 4, bp, out);
}